// Round 4
// baseline (39.975 us; speedup 1.0000x reference)
//
#include <hip/hip_runtime.h>
#include <math.h>

#define VOCAB 100000
#define EMB 128
#define BATCH 16384
#define NPOS 4
#define NNEG 20
#define NSAMP (NPOS + NNEG)   // 24
#define EPSV 1e-3f

#define NTHREADS 256
#define WPB (NTHREADS / 64)       // 4 waves/block, one batch elem per wave
#define NBLOCKS (BATCH / WPB)     // 4096

// One wave per batch element. All 24 sample indices are loaded via the SCALAR
// path (readfirstlane-forced uniform base) so gather loads are
// global_load_dwordx4 with SGPR base + one shared voffset VGPR: no shuffle or
// VALU address work on the critical path. 3 batches of 8 independent loads
// (32 VGPR of data in flight) at 32 waves/CU -> ~256 outstanding misses/CU.
__global__ __launch_bounds__(NTHREADS, 8) void w2v_main(
    const int* __restrict__ x,
    const int* __restrict__ pos,
    const int* __restrict__ neg,
    const float* __restrict__ emb,
    const float* __restrict__ outw,
    float* __restrict__ partials)
{
    const int tid  = threadIdx.x;
    const int lane = tid & 63;
    const int wid  = tid >> 6;
    const int li   = lane & 31;   // lane within half-wave

    // b is wave-uniform; force it into an SGPR so index loads scalarize.
    const int b = __builtin_amdgcn_readfirstlane((int)(blockIdx.x * WPB + wid));

    const int xb = x[b];                       // scalar load
    const int* pb = pos + b * NPOS;
    const int* nb = neg + b * NNEG;

    int sidx[NSAMP];
#pragma unroll
    for (int s = 0; s < NSAMP; ++s)
        sidx[s] = (s < NPOS) ? pb[s] : nb[s - NPOS];   // s_load_dwordx4/x8

    // emb row: lane li holds floats [4li,4li+4); halves duplicate (TA merges).
    const float4 e = ((const float4*)(emb + ((long)xb << 7)))[li];

    float pacc = 0.0f, nacc = 0.0f;

#pragma unroll
    for (int k = 0; k < 3; ++k) {
        float4 w[8];
#pragma unroll
        for (int j = 0; j < 8; ++j)
            w[j] = ((const float4*)(outw + ((long)sidx[k * 8 + j] << 7)))[li];

        float d[8];
#pragma unroll
        for (int j = 0; j < 8; ++j)
            d[j] = e.x * w[j].x + e.y * w[j].y + e.z * w[j].z + e.w * w[j].w;

        // 32-lane butterfly per sample (halves hold identical copies)
#pragma unroll
        for (int j = 0; j < 8; ++j) {
            d[j] += __shfl_xor(d[j], 1);
            d[j] += __shfl_xor(d[j], 2);
            d[j] += __shfl_xor(d[j], 4);
            d[j] += __shfl_xor(d[j], 8);
            d[j] += __shfl_xor(d[j], 16);
        }

        // lanes 0..7 finalize this batch's 8 samples (lanes 32..39 excluded
        // by `lane<8` so nothing double-counts).
        if (lane < 8) {
            float zz = d[0];
#pragma unroll
            for (int j = 1; j < 8; ++j) zz = (lane == j) ? d[j] : zz;
            const int s = k * 8 + lane;
            const float sg = 1.0f / (1.0f + __expf(-zz));   // sigmoid
            if (s < NPOS) pacc += __logf(sg);
            else          nacc += __logf(1.0f - sg + EPSV);
        }
    }

    // only lanes 0..7 hold data; xor 1/2/4 reduces them onto lane 0
    pacc += __shfl_xor(pacc, 1); pacc += __shfl_xor(pacc, 2); pacc += __shfl_xor(pacc, 4);
    nacc += __shfl_xor(nacc, 1); nacc += __shfl_xor(nacc, 2); nacc += __shfl_xor(nacc, 4);

    __shared__ float sp[WPB];
    __shared__ float sn[WPB];
    if (lane == 0) { sp[wid] = pacc; sn[wid] = nacc; }
    __syncthreads();
    if (tid == 0) {
        float tp = 0.0f, tn = 0.0f;
#pragma unroll
        for (int w2 = 0; w2 < WPB; ++w2) { tp += sp[w2]; tn += sn[w2]; }
        ((float2*)partials)[blockIdx.x] = make_float2(tp, tn);
    }
}

// Finalize: single block reduces 4096 float2 partials, writes the scalar loss.
__global__ __launch_bounds__(1024) void w2v_final(
    const float* __restrict__ partials, float* __restrict__ out)
{
    const int tid  = threadIdx.x;
    const int lane = tid & 63;
    const int wid  = tid >> 6;

    float tp = 0.0f, tn = 0.0f;
    for (int k = tid; k < NBLOCKS; k += 1024) {
        const float2 v = ((const float2*)partials)[k];
        tp += v.x;
        tn += v.y;
    }
#pragma unroll
    for (int m = 1; m < 64; m <<= 1) {
        tp += __shfl_xor(tp, m);
        tn += __shfl_xor(tn, m);
    }
    __shared__ float sp[16];
    __shared__ float sn[16];
    if (lane == 0) { sp[wid] = tp; sn[wid] = tn; }
    __syncthreads();
    if (tid == 0) {
        float fp = 0.0f, fn = 0.0f;
#pragma unroll
        for (int w2 = 0; w2 < 16; ++w2) { fp += sp[w2]; fn += sn[w2]; }
        out[0] = -fp / (float)(BATCH * NPOS) - fn / (float)(BATCH * NNEG);
    }
}

extern "C" void kernel_launch(void* const* d_in, const int* in_sizes, int n_in,
                              void* d_out, int out_size, void* d_ws, size_t ws_size,
                              hipStream_t stream) {
    const int*   x    = (const int*)d_in[0];
    const int*   pos  = (const int*)d_in[1];
    const int*   neg  = (const int*)d_in[2];
    const float* emb  = (const float*)d_in[3];
    const float* outw = (const float*)d_in[4];
    float* out = (float*)d_out;
    float* partials = (float*)d_ws;   // 4096 float2, fully rewritten each launch

    w2v_main<<<NBLOCKS, NTHREADS, 0, stream>>>(x, pos, neg, emb, outw, partials);
    w2v_final<<<1, 1024, 0, stream>>>(partials, out);
}

// Round 5
// 36.475 us; speedup vs baseline: 1.0960x; 1.0960x over previous
//
#include <hip/hip_runtime.h>
#include <math.h>

#define VOCAB 100000
#define EMB 128
#define BATCH 16384
#define NPOS 4
#define NNEG 20
#define NSAMP (NPOS + NNEG)   // 24
#define EPSV 1e-3f

#define NTHREADS 256
#define WPB (NTHREADS / 64)       // 4 waves/block, one batch elem per wave
#define NBLOCKS (BATCH / WPB)     // 4096

__device__ __forceinline__ float dot4(float4 a, float4 b) {
    return a.x * b.x + a.y * b.y + a.z * b.z + a.w * b.w;
}

// One wave per batch element, (sample x chunk) lane layout:
//   sg = lane>>3 (sample-in-group 0..7), c = lane&7 (chunk lane).
// Lane (sg,c) accumulates its sample's dot over chunks {c,c+8,c+16,c+24}
// IN-REGISTER, so the cross-lane reduce is just 3 shfl_xor over the 8-lane
// c-group (9 LDS ops/elem total vs 60+ in prior rounds). Gather insts are
// unchanged in byte terms: 4 insts per 8-sample group, each 8 rows x 128 B
// contiguous = 16 lines = 1 KB, fully coalesced.
__global__ __launch_bounds__(NTHREADS, 4) void w2v_main(
    const int* __restrict__ x,
    const int* __restrict__ pos,
    const int* __restrict__ neg,
    const float* __restrict__ emb,
    const float* __restrict__ outw,
    float* __restrict__ partials)
{
    const int tid  = threadIdx.x;
    const int lane = tid & 63;
    const int wid  = tid >> 6;
    const int sg   = lane >> 3;   // 0..7
    const int c    = lane & 7;    // 0..7

    const int b  = blockIdx.x * WPB + wid;  // batch element (wave-uniform)
    const int xb = x[b];

    // Per-lane sample indices for the 3 groups: sample j = g*8 + sg.
    // 8 lanes share each address (TA dedups); 1-2 lines per load.
    int idx0, idx1, idx2;
    {
        const int j0 = sg;
        idx0 = (j0 < NPOS) ? pos[b * NPOS + j0] : neg[b * NNEG + (j0 - NPOS)];
        idx1 = neg[b * NNEG + (8  + sg - NPOS)];
        idx2 = neg[b * NNEG + (16 + sg - NPOS)];
    }

    // emb chunks this lane needs: c, c+8, c+16, c+24 (8-way dup per inst).
    const float4* er = (const float4*)(emb + ((long)xb << 7));
    const float4 e0 = er[c];
    const float4 e1 = er[c + 8];
    const float4 e2 = er[c + 16];
    const float4 e3 = er[c + 24];

    float pacc = 0.0f, nacc = 0.0f;

#pragma unroll
    for (int g = 0; g < 3; ++g) {
        const int row = (g == 0) ? idx0 : ((g == 1) ? idx1 : idx2);
        const float4* wr = (const float4*)(outw + ((long)row << 7));
        const float4 w0 = wr[c];
        const float4 w1 = wr[c + 8];
        const float4 w2 = wr[c + 16];
        const float4 w3 = wr[c + 24];

        float d = dot4(e0, w0) + dot4(e1, w1) + dot4(e2, w2) + dot4(e3, w3);

        // reduce over the 8-lane c-group (masks < 8 stay within the group)
        d += __shfl_xor(d, 1);
        d += __shfl_xor(d, 2);
        d += __shfl_xor(d, 4);

        // lane c==0 finalizes sample s = g*8 + sg
        if (c == 0) {
            const int s = g * 8 + sg;
            const float sig = 1.0f / (1.0f + __expf(-d));
            if (s < NPOS) pacc += __logf(sig);
            else          nacc += __logf(1.0f - sig + EPSV);
        }
    }

    // Sum over lanes {0,8,...,56} (c!=0 lanes hold 0): masks 8,16,32.
    pacc += __shfl_xor(pacc, 8); pacc += __shfl_xor(pacc, 16); pacc += __shfl_xor(pacc, 32);
    nacc += __shfl_xor(nacc, 8); nacc += __shfl_xor(nacc, 16); nacc += __shfl_xor(nacc, 32);

    __shared__ float sp[WPB];
    __shared__ float sn[WPB];
    if (lane == 0) { sp[wid] = pacc; sn[wid] = nacc; }
    __syncthreads();
    if (tid == 0) {
        float tp = 0.0f, tn = 0.0f;
#pragma unroll
        for (int w = 0; w < WPB; ++w) { tp += sp[w]; tn += sn[w]; }
        ((float2*)partials)[blockIdx.x] = make_float2(tp, tn);
    }
}

// Finalize: single block reduces 4096 float2 partials, writes the scalar loss.
__global__ __launch_bounds__(1024) void w2v_final(
    const float* __restrict__ partials, float* __restrict__ out)
{
    const int tid  = threadIdx.x;
    const int lane = tid & 63;
    const int wid  = tid >> 6;

    float tp = 0.0f, tn = 0.0f;
    for (int k = tid; k < NBLOCKS; k += 1024) {
        const float2 v = ((const float2*)partials)[k];
        tp += v.x;
        tn += v.y;
    }
#pragma unroll
    for (int m = 1; m < 64; m <<= 1) {
        tp += __shfl_xor(tp, m);
        tn += __shfl_xor(tn, m);
    }
    __shared__ float sp[16];
    __shared__ float sn[16];
    if (lane == 0) { sp[wid] = tp; sn[wid] = tn; }
    __syncthreads();
    if (tid == 0) {
        float fp = 0.0f, fn = 0.0f;
#pragma unroll
        for (int w = 0; w < 16; ++w) { fp += sp[w]; fn += sn[w]; }
        out[0] = -fp / (float)(BATCH * NPOS) - fn / (float)(BATCH * NNEG);
    }
}

extern "C" void kernel_launch(void* const* d_in, const int* in_sizes, int n_in,
                              void* d_out, int out_size, void* d_ws, size_t ws_size,
                              hipStream_t stream) {
    const int*   x    = (const int*)d_in[0];
    const int*   pos  = (const int*)d_in[1];
    const int*   neg  = (const int*)d_in[2];
    const float* emb  = (const float*)d_in[3];
    const float* outw = (const float*)d_in[4];
    float* out = (float*)d_out;
    float* partials = (float*)d_ws;   // 4096 float2, fully rewritten each launch

    w2v_main<<<NBLOCKS, NTHREADS, 0, stream>>>(x, pos, neg, emb, outw, partials);
    w2v_final<<<1, 1024, 0, stream>>>(partials, out);
}